// Round 13
// baseline (66.167 us; speedup 1.0000x reference)
//
#include <hip/hip_runtime.h>
#include <hip/hip_bf16.h>

typedef unsigned short u16;
typedef unsigned int   u32;

#define MM 8192
#define DD 128
#define NB 64                    // 128-row bands
#define NTRI (NB * (NB + 1) / 2) // 2080 upper-triangle blocks
#define SKIP_THR -40.0f

using short8 = __attribute__((ext_vector_type(8))) short;
using f32x4  = __attribute__((ext_vector_type(4))) float;

__device__ __forceinline__ u16 f2bf(float f) {
  u32 u = __float_as_uint(f);
  u32 r = u + 0x7fffu + ((u >> 16) & 1u);   // RNE
  return (u16)(r >> 16);
}

#define GLOAD_LDS16(g, l)                                          \
  __builtin_amdgcn_global_load_lds(                                \
      (const __attribute__((address_space(1))) void*)(g),          \
      (__attribute__((address_space(3))) void*)(l), 16, 0, 0)

// One wave per 2 rows (float4 loads): bf16 conversion + squared norms.
__global__ __launch_bounds__(256) void convert_kernel(
    const float* __restrict__ x, const float* __restrict__ y,
    u16* __restrict__ xb, u16* __restrict__ yb,
    float* __restrict__ sqx, float* __restrict__ sqy)
{
  const int wid  = threadIdx.x >> 6;
  const int lane = threadIdx.x & 63;
  const int l32  = lane & 31;
  const int row  = blockIdx.x * 8 + wid * 2 + (lane >> 5);
  const float4 vx = *(const float4*)(x + (size_t)row * DD + l32 * 4);
  const float4 vy = *(const float4*)(y + (size_t)row * DD + l32 * 4);
  float sx = vx.x * vx.x + vx.y * vx.y + vx.z * vx.z + vx.w * vx.w;
  float sy = vy.x * vy.x + vy.y * vy.y + vy.z * vy.z + vy.w * vy.w;
  #pragma unroll
  for (int off = 1; off < 32; off <<= 1) {
    sx += __shfl_xor(sx, off, 64);
    sy += __shfl_xor(sy, off, 64);
  }
  uint2 px, py;
  px.x = (u32)f2bf(vx.x) | ((u32)f2bf(vx.y) << 16);
  px.y = (u32)f2bf(vx.z) | ((u32)f2bf(vx.w) << 16);
  py.x = (u32)f2bf(vy.x) | ((u32)f2bf(vy.y) << 16);
  py.y = (u32)f2bf(vy.z) | ((u32)f2bf(vy.w) << 16);
  *(uint2*)(xb + (size_t)row * DD + l32 * 4) = px;
  *(uint2*)(yb + (size_t)row * DD + l32 * 4) = py;
  if (l32 == 0) { sqx[row] = sx; sqy[row] = sy; }
}

// Upper-triangle 128x128 blocks (ib <= jb), 8 waves in 2x4, wave = 64x32.
// R12 structure (XCD-bijective swizzle, merged X-drain, BK=64 dbuf, 0
// conflicts, 16 waves/CU) + bound-based skip-vote on raw accumulators:
//   2*max(acc) - min(row norms) - col norm < THR  =>  all exp < THR (safe).
// Removes the ex/ey FMAs from the ~always-taken skip path.
__global__ __launch_bounds__(512) void hsic_pair_kernel(
    const u16* __restrict__ xb, const u16* __restrict__ yb,
    const float* __restrict__ sqx, const float* __restrict__ sqy,
    float* __restrict__ comb_s, float* __restrict__ comb_t,
    float* __restrict__ P_part)
{
  const int orig = blockIdx.x;
  const int bid  = (orig & 7) * (NTRI / 8) + (orig >> 3);   // XCD-chunked, bijective

  // bid -> (ib, jb), ib <= jb: closed form + +-1 fixup.
  int ib = (int)((2.0 * NB + 1.0 -
                  sqrt((2.0 * NB + 1.0) * (2.0 * NB + 1.0) - 8.0 * (double)bid)) * 0.5);
  if (ib > NB - 1) ib = NB - 1;
  if (ib < 0) ib = 0;
  if (ib * NB - ib * (ib - 1) / 2 > bid) --ib;
  if ((ib + 1) * NB - (ib + 1) * ib / 2 <= bid) ++ib;
  const int jb = ib + (bid - (ib * NB - ib * (ib - 1) / 2));

  const int tid  = threadIdx.x;
  const int wid  = tid >> 6;     // 0..7
  const int lane = tid & 63;
  const int wr   = wid >> 2;     // 0..1  (64-row group)
  const int wc   = wid & 3;      // 0..3  (32-col group)
  const int g    = lane >> 4;    // 0..3
  const int c    = lane & 15;    // 0..15

  const int ri = ib * 128 + wr * 64;
  const int cj = jb * 128 + wc * 32;

  __shared__ u16 lT[2][2][128 * 64];   // [buf][A/B][128 x 64] = 64 KB
  __shared__ float lds_sr[128], lds_sc[128], lds_tr[128], lds_tc[128];
  __shared__ float red[8];
  if (tid < 128) {
    lds_sr[tid] = 0.f; lds_sc[tid] = 0.f;
    lds_tr[tid] = 0.f; lds_tc[tid] = 0.f;
  }

  // Staging geometry (per 16KB sub-tile): 2 x 16B chunks per thread.
  // LDS dest linear: o = i*8192 + tid*16. Source pre-swizzled:
  //   r = o>>7, ch = (o>>4)&7, src = r*256 + (ch ^ (r&7))*16 (+kh*128).
  int so_[2];
  #pragma unroll
  for (int i = 0; i < 2; ++i) {
    const int o  = i * 8192 + tid * 16;
    const int r  = o >> 7;
    const int ch = (o >> 4) & 7;
    so_[i] = r * 256 + ((ch ^ (r & 7)) << 4);
  }

#define STAGE(BUF, GA, GB, KH) do {                                     \
    const char* gA_ = (GA) + (KH) * 128;                                \
    const char* gB_ = (GB) + (KH) * 128;                                \
    char* dA_ = (char*)&lT[BUF][0][0] + wid * 1024;                     \
    char* dB_ = (char*)&lT[BUF][1][0] + wid * 1024;                     \
    _Pragma("unroll") for (int i = 0; i < 2; ++i) {                     \
      GLOAD_LDS16(gA_ + so_[i], dA_ + i * 8192);                        \
      GLOAD_LDS16(gB_ + so_[i], dB_ + i * 8192);                        \
    }                                                                   \
  } while (0)

  // Fragment read in a 16KB sub-tile: elem = row*64 + (ch ^ (row&7))*8.
#define FRAG2(Lp, row, ch) \
  (*(const short8*)((Lp) + (((row) << 6) + (((ch) ^ ((row) & 7)) << 3))))

#define COMPUTE(ACC, BUF) do {                                          \
    _Pragma("unroll") for (int kk2 = 0; kk2 < 2; ++kk2) {               \
      short8 bfr[2], afr[4];                                            \
      _Pragma("unroll") for (int cs = 0; cs < 2; ++cs)                  \
        bfr[cs] = FRAG2(&lT[BUF][1][0], wc * 32 + cs * 16 + c, kk2 * 4 + g); \
      _Pragma("unroll") for (int rs = 0; rs < 4; ++rs)                  \
        afr[rs] = FRAG2(&lT[BUF][0][0], wr * 64 + rs * 16 + c, kk2 * 4 + g); \
      _Pragma("unroll") for (int rs = 0; rs < 4; ++rs)                  \
        _Pragma("unroll") for (int cs = 0; cs < 2; ++cs)                \
          ACC[rs][cs] = __builtin_amdgcn_mfma_f32_16x16x32_bf16(        \
              afr[rs], bfr[cs], ACC[rs][cs], 0, 0, 0);                  \
    }                                                                   \
  } while (0)

  const char* gAx = (const char*)xb + (size_t)(ib * 128) * 256;
  const char* gBx = (const char*)xb + (size_t)(jb * 128) * 256;
  const char* gAy = (const char*)yb + (size_t)(ib * 128) * 256;
  const char* gBy = (const char*)yb + (size_t)(jb * 128) * 256;

  f32x4 accX[4][2];
  f32x4 accY[4][2];
  #pragma unroll
  for (int rs = 0; rs < 4; ++rs)
    #pragma unroll
    for (int cs = 0; cs < 2; ++cs) {
      accX[rs][cs] = (f32x4){0.f, 0.f, 0.f, 0.f};
      accY[rs][cs] = (f32x4){0.f, 0.f, 0.f, 0.f};
    }

  // Pipeline (4 main barriers): both X stages drain together; Y stages
  // fly under X/Y computes.
  STAGE(0, gAx, gBx, 0);
  STAGE(1, gAx, gBx, 1);
  __syncthreads();                       // one drain for both X sub-tiles
  COMPUTE(accX, 0);
  __syncthreads();                       // all waves done reading buf0
  STAGE(0, gAy, gBy, 0);                 // Y0 flies under X1 compute
  COMPUTE(accX, 1);
  __syncthreads();                       // drains Y0; buf1 reads done
  STAGE(1, gAy, gBy, 1);                 // Y1 flies under Y0 compute
  COMPUTE(accY, 0);
  __syncthreads();                       // drains Y1
  COMPUTE(accY, 1);

  // ---- epilogue ----
  float sqxc[2], sqyc[2];
  #pragma unroll
  for (int cs = 0; cs < 2; ++cs) {
    sqxc[cs] = sqx[cj + cs * 16 + c];
    sqyc[cs] = sqy[cj + cs * 16 + c];
  }

  float p_acc = 0.f;
  float scol_acc[2] = {0.f, 0.f};
  float tcol_acc[2] = {0.f, 0.f};

  #pragma unroll
  for (int rs = 0; rs < 4; ++rs) {
    const f32x4 sxr = *(const f32x4*)(sqx + ri + rs * 16 + g * 4);
    const f32x4 syr = *(const f32x4*)(sqy + ri + rs * 16 + g * 4);
    const float sxr_min = fminf(fminf(sxr[0], sxr[1]), fminf(sxr[2], sxr[3]));
    const float syr_min = fminf(fminf(syr[0], syr[1]), fminf(syr[2], syr[3]));

    float sr_acc[4] = {0.f, 0.f, 0.f, 0.f};
    float tr_acc[4] = {0.f, 0.f, 0.f, 0.f};
    bool rowx = false, rowy = false;

    #pragma unroll
    for (int cs = 0; cs < 2; ++cs) {
      // Bound-based vote: 2*max(acc) - min(sxr) - sqxc >= true max exponent.
      const float mxx = fmaxf(fmaxf(accX[rs][cs][0], accX[rs][cs][1]),
                              fmaxf(accX[rs][cs][2], accX[rs][cs][3]));
      const float mxy = fmaxf(fmaxf(accY[rs][cs][0], accY[rs][cs][1]),
                              fmaxf(accY[rs][cs][2], accY[rs][cs][3]));
      const bool skipx = __all(2.f * mxx - sxr_min - sqxc[cs] < SKIP_THR);
      const bool skipy = __all(2.f * mxy - syr_min - sqyc[cs] < SKIP_THR);
      if (skipx && skipy) continue;   // wave-uniform

      const int gc = cj + cs * 16 + c;
      float kx[4], ly[4];
      #pragma unroll
      for (int tt = 0; tt < 4; ++tt) {
        const int gr = ri + rs * 16 + g * 4 + tt;
        kx[tt] = skipx ? 0.f
               : ((gr == gc) ? 1.f
                             : __expf(2.f * accX[rs][cs][tt] - sxr[tt] - sqxc[cs]));
        ly[tt] = skipy ? 0.f
               : ((gr == gc) ? 1.f
                             : __expf(2.f * accY[rs][cs][tt] - syr[tt] - sqyc[cs]));
      }
      if (!skipx) {
        rowx = true;
        float sc_ = 0.f;
        #pragma unroll
        for (int tt = 0; tt < 4; ++tt) { sr_acc[tt] += kx[tt]; sc_ += kx[tt]; }
        sc_ += __shfl_xor(sc_, 16, 64);   // reduce over g-lanes
        sc_ += __shfl_xor(sc_, 32, 64);
        scol_acc[cs] += sc_;
      }
      if (!skipy) {
        rowy = true;
        float tc_ = 0.f;
        #pragma unroll
        for (int tt = 0; tt < 4; ++tt) { tr_acc[tt] += ly[tt]; tc_ += ly[tt]; }
        tc_ += __shfl_xor(tc_, 16, 64);
        tc_ += __shfl_xor(tc_, 32, 64);
        tcol_acc[cs] += tc_;
      }
      if (!skipx && !skipy) {
        #pragma unroll
        for (int tt = 0; tt < 4; ++tt) p_acc += kx[tt] * ly[tt];
      }
    }

    if (rowx) {
      #pragma unroll
      for (int tt = 0; tt < 4; ++tt) {
        float sv = sr_acc[tt];
        #pragma unroll
        for (int off = 1; off < 16; off <<= 1) sv += __shfl_xor(sv, off, 64);
        if (c == 0) atomicAdd(&lds_sr[wr * 64 + rs * 16 + g * 4 + tt], sv);
      }
    }
    if (rowy) {
      #pragma unroll
      for (int tt = 0; tt < 4; ++tt) {
        float tv = tr_acc[tt];
        #pragma unroll
        for (int off = 1; off < 16; off <<= 1) tv += __shfl_xor(tv, off, 64);
        if (c == 0) atomicAdd(&lds_tr[wr * 64 + rs * 16 + g * 4 + tt], tv);
      }
    }
  }

  // Column sums (band jb rows via symmetry).
  if (g == 0) {
    #pragma unroll
    for (int cs = 0; cs < 2; ++cs) {
      atomicAdd(&lds_sc[wc * 32 + cs * 16 + c], scol_acc[cs]);
      atomicAdd(&lds_tc[wc * 32 + cs * 16 + c], tcol_acc[cs]);
    }
  }

  // Block-reduce P.
  #pragma unroll
  for (int off = 1; off < 64; off <<= 1) p_acc += __shfl_xor(p_acc, off, 64);
  if (lane == 0) red[wid] = p_acc;
  __syncthreads();

  // Band-keyed plain stores: row-part -> comb[ib][jb], col-part -> comb[jb][ib].
  if (tid < 128) {
    comb_s[((size_t)ib * NB + jb) * 128 + tid] = lds_sr[tid];
    comb_t[((size_t)ib * NB + jb) * 128 + tid] = lds_tr[tid];
    if (ib != jb) {
      comb_s[((size_t)jb * NB + ib) * 128 + tid] = lds_sc[tid];
      comb_t[((size_t)jb * NB + ib) * 128 + tid] = lds_tc[tid];
    }
  }
  if (tid == 0) {
    const float w = (ib == jb) ? 1.f : 2.f;
    P_part[bid] = w * (red[0] + red[1] + red[2] + red[3] +
                       red[4] + red[5] + red[6] + red[7]);
  }
}

// 64 blocks x 512 threads: per band, fold 64 part-vectors -> band partials;
// LAST finished block (atomic ticket) does the final formula. One launch.
__global__ __launch_bounds__(512) void reduce_kernel(
    const float* __restrict__ comb_s, const float* __restrict__ comb_t,
    const float* __restrict__ P_part, float* __restrict__ band_acc,
    u32* __restrict__ counter, float* __restrict__ out)
{
  const int b   = blockIdx.x;
  const int tid = threadIdx.x;
  const int row = tid & 127;
  const int grp = tid >> 7;    // 0..3

  float sv = 0.f, tv = 0.f;
  for (int k = grp * 16; k < grp * 16 + 16; ++k) {
    sv += comb_s[((size_t)b * NB + k) * 128 + row];
    tv += comb_t[((size_t)b * NB + k) * 128 + row];
  }
  __shared__ float ls[4][128], lt[4][128];
  ls[grp][row] = sv;
  lt[grp][row] = tv;
  __syncthreads();

  __shared__ float r2[2][3];
  if (tid < 128) {
    float S = ls[0][row] + ls[1][row] + ls[2][row] + ls[3][row];
    float T = lt[0][row] + lt[1][row] + lt[2][row] + lt[3][row];
    float C = S * T;
    #pragma unroll
    for (int off = 1; off < 64; off <<= 1) {
      S += __shfl_xor(S, off, 64);
      T += __shfl_xor(T, off, 64);
      C += __shfl_xor(C, off, 64);
    }
    if ((tid & 63) == 0) { r2[tid >> 6][0] = S; r2[tid >> 6][1] = T; r2[tid >> 6][2] = C; }
  }
  __syncthreads();
  if (tid == 0) {
    band_acc[b * 4 + 0] = r2[0][0] + r2[1][0];
    band_acc[b * 4 + 1] = r2[0][1] + r2[1][1];
    band_acc[b * 4 + 2] = r2[0][2] + r2[1][2];
  }

  // Last-block-done final reduction.
  __shared__ u32 ticket;
  __threadfence();
  if (tid == 0) ticket = atomicAdd(counter, 1u);
  __syncthreads();
  if (ticket != NB - 1) return;
  __threadfence();

  float S = 0.f, T = 0.f, C = 0.f, P = 0.f;
  if (tid < NB) {
    S = band_acc[tid * 4 + 0];
    T = band_acc[tid * 4 + 1];
    C = band_acc[tid * 4 + 2];
  }
  for (int i = tid; i < NTRI; i += 512) P += P_part[i];
  #pragma unroll
  for (int off = 1; off < 64; off <<= 1) {
    S += __shfl_xor(S, off, 64);
    T += __shfl_xor(T, off, 64);
    C += __shfl_xor(C, off, 64);
    P += __shfl_xor(P, off, 64);
  }
  __shared__ float r[8][4];
  const int w = tid >> 6;
  if ((tid & 63) == 0) { r[w][0] = S; r[w][1] = T; r[w][2] = C; r[w][3] = P; }
  __syncthreads();
  if (tid == 0) {
    double St = 0.0, Tt = 0.0, Ct = 0.0, Pt = 0.0;
    for (int i = 0; i < 8; ++i) {
      St += r[i][0]; Tt += r[i][1]; Ct += r[i][2]; Pt += r[i][3];
    }
    const double m  = (double)MM;
    const double num = Pt - (2.0 / m) * Ct + (St * Tt) / (m * m);
    out[0] = (float)(num / ((m - 1.0) * (m - 1.0)));
  }
}

extern "C" void kernel_launch(void* const* d_in, const int* in_sizes, int n_in,
                              void* d_out, int out_size, void* d_ws, size_t ws_size,
                              hipStream_t stream) {
  const float* x = (const float*)d_in[0];
  const float* y = (const float*)d_in[1];

  char* ws = (char*)d_ws;
  u16*   xb       = (u16*)ws;                                      // 2 MB
  u16*   yb       = (u16*)(ws + (size_t)2 * 1024 * 1024);          // 2 MB
  float* sqx      = (float*)(ws + (size_t)4 * 1024 * 1024);        // 32 KB
  float* sqy      = sqx + MM;                                      // 32 KB
  float* comb_s   = sqy + MM;                                      // 2 MB
  float* comb_t   = comb_s + (size_t)NB * NB * 128;                // 2 MB
  float* P_part   = comb_t + (size_t)NB * NB * 128;                // 8.3 KB
  float* band_acc = P_part + NTRI;                                 // 1 KB
  u32*   counter  = (u32*)(band_acc + NB * 4);                     // 4 B

  hipMemsetAsync(counter, 0, sizeof(u32), stream);

  convert_kernel<<<MM / 8, 256, 0, stream>>>(x, y, xb, yb, sqx, sqy);

  hsic_pair_kernel<<<NTRI, 512, 0, stream>>>(xb, yb, sqx, sqy, comb_s, comb_t, P_part);

  reduce_kernel<<<NB, 512, 0, stream>>>(comb_s, comb_t, P_part, band_acc,
                                        counter, (float*)d_out);
}

// Round 14
// 60.240 us; speedup vs baseline: 1.0984x; 1.0984x over previous
//
#include <hip/hip_runtime.h>
#include <hip/hip_bf16.h>

typedef unsigned short u16;
typedef unsigned int   u32;

#define MM 8192
#define DD 128
#define NB 64                    // 128-row bands
#define NTRI (NB * (NB + 1) / 2) // 2080 upper-triangle blocks
#define SKIP_THR -40.0f

using short8 = __attribute__((ext_vector_type(8))) short;
using f32x4  = __attribute__((ext_vector_type(4))) float;

__device__ __forceinline__ u16 f2bf(float f) {
  u32 u = __float_as_uint(f);
  u32 r = u + 0x7fffu + ((u >> 16) & 1u);   // RNE
  return (u16)(r >> 16);
}

#define GLOAD_LDS16(g, l)                                          \
  __builtin_amdgcn_global_load_lds(                                \
      (const __attribute__((address_space(1))) void*)(g),          \
      (__attribute__((address_space(3))) void*)(l), 16, 0, 0)

// One wave per 2 rows (float4 loads): bf16 conversion + squared norms.
__global__ __launch_bounds__(256) void convert_kernel(
    const float* __restrict__ x, const float* __restrict__ y,
    u16* __restrict__ xb, u16* __restrict__ yb,
    float* __restrict__ sqx, float* __restrict__ sqy)
{
  const int wid  = threadIdx.x >> 6;
  const int lane = threadIdx.x & 63;
  const int l32  = lane & 31;
  const int row  = blockIdx.x * 8 + wid * 2 + (lane >> 5);
  const float4 vx = *(const float4*)(x + (size_t)row * DD + l32 * 4);
  const float4 vy = *(const float4*)(y + (size_t)row * DD + l32 * 4);
  float sx = vx.x * vx.x + vx.y * vx.y + vx.z * vx.z + vx.w * vx.w;
  float sy = vy.x * vy.x + vy.y * vy.y + vy.z * vy.z + vy.w * vy.w;
  #pragma unroll
  for (int off = 1; off < 32; off <<= 1) {
    sx += __shfl_xor(sx, off, 64);
    sy += __shfl_xor(sy, off, 64);
  }
  uint2 px, py;
  px.x = (u32)f2bf(vx.x) | ((u32)f2bf(vx.y) << 16);
  px.y = (u32)f2bf(vx.z) | ((u32)f2bf(vx.w) << 16);
  py.x = (u32)f2bf(vy.x) | ((u32)f2bf(vy.y) << 16);
  py.y = (u32)f2bf(vy.z) | ((u32)f2bf(vy.w) << 16);
  *(uint2*)(xb + (size_t)row * DD + l32 * 4) = px;
  *(uint2*)(yb + (size_t)row * DD + l32 * 4) = py;
  if (l32 == 0) { sqx[row] = sx; sqy[row] = sy; }
}

// Upper-triangle 128x128 blocks (ib <= jb), 8 waves in 2x4, wave = 64x32.
// R12 structure (XCD-bijective swizzle, merged X-drain, BK=64 dbuf, 0
// conflicts, 16 waves/CU) + bound-based skip-vote on raw accumulators:
//   2*max(acc) - min(row norms) - col norm < THR  =>  all exp < THR (safe).
__global__ __launch_bounds__(512) void hsic_pair_kernel(
    const u16* __restrict__ xb, const u16* __restrict__ yb,
    const float* __restrict__ sqx, const float* __restrict__ sqy,
    float* __restrict__ comb_s, float* __restrict__ comb_t,
    float* __restrict__ P_part)
{
  const int orig = blockIdx.x;
  const int bid  = (orig & 7) * (NTRI / 8) + (orig >> 3);   // XCD-chunked, bijective

  // bid -> (ib, jb), ib <= jb: closed form + +-1 fixup.
  int ib = (int)((2.0 * NB + 1.0 -
                  sqrt((2.0 * NB + 1.0) * (2.0 * NB + 1.0) - 8.0 * (double)bid)) * 0.5);
  if (ib > NB - 1) ib = NB - 1;
  if (ib < 0) ib = 0;
  if (ib * NB - ib * (ib - 1) / 2 > bid) --ib;
  if ((ib + 1) * NB - (ib + 1) * ib / 2 <= bid) ++ib;
  const int jb = ib + (bid - (ib * NB - ib * (ib - 1) / 2));

  const int tid  = threadIdx.x;
  const int wid  = tid >> 6;     // 0..7
  const int lane = tid & 63;
  const int wr   = wid >> 2;     // 0..1  (64-row group)
  const int wc   = wid & 3;      // 0..3  (32-col group)
  const int g    = lane >> 4;    // 0..3
  const int c    = lane & 15;    // 0..15

  const int ri = ib * 128 + wr * 64;
  const int cj = jb * 128 + wc * 32;

  __shared__ u16 lT[2][2][128 * 64];   // [buf][A/B][128 x 64] = 64 KB
  __shared__ float lds_sr[128], lds_sc[128], lds_tr[128], lds_tc[128];
  __shared__ float red[8];
  if (tid < 128) {
    lds_sr[tid] = 0.f; lds_sc[tid] = 0.f;
    lds_tr[tid] = 0.f; lds_tc[tid] = 0.f;
  }

  // Staging geometry (per 16KB sub-tile): 2 x 16B chunks per thread.
  // LDS dest linear: o = i*8192 + tid*16. Source pre-swizzled:
  //   r = o>>7, ch = (o>>4)&7, src = r*256 + (ch ^ (r&7))*16 (+kh*128).
  int so_[2];
  #pragma unroll
  for (int i = 0; i < 2; ++i) {
    const int o  = i * 8192 + tid * 16;
    const int r  = o >> 7;
    const int ch = (o >> 4) & 7;
    so_[i] = r * 256 + ((ch ^ (r & 7)) << 4);
  }

#define STAGE(BUF, GA, GB, KH) do {                                     \
    const char* gA_ = (GA) + (KH) * 128;                                \
    const char* gB_ = (GB) + (KH) * 128;                                \
    char* dA_ = (char*)&lT[BUF][0][0] + wid * 1024;                     \
    char* dB_ = (char*)&lT[BUF][1][0] + wid * 1024;                     \
    _Pragma("unroll") for (int i = 0; i < 2; ++i) {                     \
      GLOAD_LDS16(gA_ + so_[i], dA_ + i * 8192);                        \
      GLOAD_LDS16(gB_ + so_[i], dB_ + i * 8192);                        \
    }                                                                   \
  } while (0)

  // Fragment read in a 16KB sub-tile: elem = row*64 + (ch ^ (row&7))*8.
#define FRAG2(Lp, row, ch) \
  (*(const short8*)((Lp) + (((row) << 6) + (((ch) ^ ((row) & 7)) << 3))))

#define COMPUTE(ACC, BUF) do {                                          \
    _Pragma("unroll") for (int kk2 = 0; kk2 < 2; ++kk2) {               \
      short8 bfr[2], afr[4];                                            \
      _Pragma("unroll") for (int cs = 0; cs < 2; ++cs)                  \
        bfr[cs] = FRAG2(&lT[BUF][1][0], wc * 32 + cs * 16 + c, kk2 * 4 + g); \
      _Pragma("unroll") for (int rs = 0; rs < 4; ++rs)                  \
        afr[rs] = FRAG2(&lT[BUF][0][0], wr * 64 + rs * 16 + c, kk2 * 4 + g); \
      _Pragma("unroll") for (int rs = 0; rs < 4; ++rs)                  \
        _Pragma("unroll") for (int cs = 0; cs < 2; ++cs)                \
          ACC[rs][cs] = __builtin_amdgcn_mfma_f32_16x16x32_bf16(        \
              afr[rs], bfr[cs], ACC[rs][cs], 0, 0, 0);                  \
    }                                                                   \
  } while (0)

  const char* gAx = (const char*)xb + (size_t)(ib * 128) * 256;
  const char* gBx = (const char*)xb + (size_t)(jb * 128) * 256;
  const char* gAy = (const char*)yb + (size_t)(ib * 128) * 256;
  const char* gBy = (const char*)yb + (size_t)(jb * 128) * 256;

  f32x4 accX[4][2];
  f32x4 accY[4][2];
  #pragma unroll
  for (int rs = 0; rs < 4; ++rs)
    #pragma unroll
    for (int cs = 0; cs < 2; ++cs) {
      accX[rs][cs] = (f32x4){0.f, 0.f, 0.f, 0.f};
      accY[rs][cs] = (f32x4){0.f, 0.f, 0.f, 0.f};
    }

  // Pipeline (4 main barriers): both X stages drain together; Y stages
  // fly under X/Y computes.
  STAGE(0, gAx, gBx, 0);
  STAGE(1, gAx, gBx, 1);
  __syncthreads();                       // one drain for both X sub-tiles
  COMPUTE(accX, 0);
  __syncthreads();                       // all waves done reading buf0
  STAGE(0, gAy, gBy, 0);                 // Y0 flies under X1 compute
  COMPUTE(accX, 1);
  __syncthreads();                       // drains Y0; buf1 reads done
  STAGE(1, gAy, gBy, 1);                 // Y1 flies under Y0 compute
  COMPUTE(accY, 0);
  __syncthreads();                       // drains Y1
  COMPUTE(accY, 1);

  // ---- epilogue ----
  float sqxc[2], sqyc[2];
  #pragma unroll
  for (int cs = 0; cs < 2; ++cs) {
    sqxc[cs] = sqx[cj + cs * 16 + c];
    sqyc[cs] = sqy[cj + cs * 16 + c];
  }

  float p_acc = 0.f;
  float scol_acc[2] = {0.f, 0.f};
  float tcol_acc[2] = {0.f, 0.f};

  #pragma unroll
  for (int rs = 0; rs < 4; ++rs) {
    const f32x4 sxr = *(const f32x4*)(sqx + ri + rs * 16 + g * 4);
    const f32x4 syr = *(const f32x4*)(sqy + ri + rs * 16 + g * 4);
    const float sxr_min = fminf(fminf(sxr[0], sxr[1]), fminf(sxr[2], sxr[3]));
    const float syr_min = fminf(fminf(syr[0], syr[1]), fminf(syr[2], syr[3]));

    float sr_acc[4] = {0.f, 0.f, 0.f, 0.f};
    float tr_acc[4] = {0.f, 0.f, 0.f, 0.f};
    bool rowx = false, rowy = false;

    #pragma unroll
    for (int cs = 0; cs < 2; ++cs) {
      // Bound-based vote: 2*max(acc) - min(sxr) - sqxc >= true max exponent.
      const float mxx = fmaxf(fmaxf(accX[rs][cs][0], accX[rs][cs][1]),
                              fmaxf(accX[rs][cs][2], accX[rs][cs][3]));
      const float mxy = fmaxf(fmaxf(accY[rs][cs][0], accY[rs][cs][1]),
                              fmaxf(accY[rs][cs][2], accY[rs][cs][3]));
      const bool skipx = __all(2.f * mxx - sxr_min - sqxc[cs] < SKIP_THR);
      const bool skipy = __all(2.f * mxy - syr_min - sqyc[cs] < SKIP_THR);
      if (skipx && skipy) continue;   // wave-uniform

      const int gc = cj + cs * 16 + c;
      float kx[4], ly[4];
      #pragma unroll
      for (int tt = 0; tt < 4; ++tt) {
        const int gr = ri + rs * 16 + g * 4 + tt;
        kx[tt] = skipx ? 0.f
               : ((gr == gc) ? 1.f
                             : __expf(2.f * accX[rs][cs][tt] - sxr[tt] - sqxc[cs]));
        ly[tt] = skipy ? 0.f
               : ((gr == gc) ? 1.f
                             : __expf(2.f * accY[rs][cs][tt] - syr[tt] - sqyc[cs]));
      }
      if (!skipx) {
        rowx = true;
        float sc_ = 0.f;
        #pragma unroll
        for (int tt = 0; tt < 4; ++tt) { sr_acc[tt] += kx[tt]; sc_ += kx[tt]; }
        sc_ += __shfl_xor(sc_, 16, 64);   // reduce over g-lanes
        sc_ += __shfl_xor(sc_, 32, 64);
        scol_acc[cs] += sc_;
      }
      if (!skipy) {
        rowy = true;
        float tc_ = 0.f;
        #pragma unroll
        for (int tt = 0; tt < 4; ++tt) { tr_acc[tt] += ly[tt]; tc_ += ly[tt]; }
        tc_ += __shfl_xor(tc_, 16, 64);
        tc_ += __shfl_xor(tc_, 32, 64);
        tcol_acc[cs] += tc_;
      }
      if (!skipx && !skipy) {
        #pragma unroll
        for (int tt = 0; tt < 4; ++tt) p_acc += kx[tt] * ly[tt];
      }
    }

    if (rowx) {
      #pragma unroll
      for (int tt = 0; tt < 4; ++tt) {
        float sv = sr_acc[tt];
        #pragma unroll
        for (int off = 1; off < 16; off <<= 1) sv += __shfl_xor(sv, off, 64);
        if (c == 0) atomicAdd(&lds_sr[wr * 64 + rs * 16 + g * 4 + tt], sv);
      }
    }
    if (rowy) {
      #pragma unroll
      for (int tt = 0; tt < 4; ++tt) {
        float tv = tr_acc[tt];
        #pragma unroll
        for (int off = 1; off < 16; off <<= 1) tv += __shfl_xor(tv, off, 64);
        if (c == 0) atomicAdd(&lds_tr[wr * 64 + rs * 16 + g * 4 + tt], tv);
      }
    }
  }

  // Column sums (band jb rows via symmetry).
  if (g == 0) {
    #pragma unroll
    for (int cs = 0; cs < 2; ++cs) {
      atomicAdd(&lds_sc[wc * 32 + cs * 16 + c], scol_acc[cs]);
      atomicAdd(&lds_tc[wc * 32 + cs * 16 + c], tcol_acc[cs]);
    }
  }

  // Block-reduce P.
  #pragma unroll
  for (int off = 1; off < 64; off <<= 1) p_acc += __shfl_xor(p_acc, off, 64);
  if (lane == 0) red[wid] = p_acc;
  __syncthreads();

  // Band-keyed plain stores: row-part -> comb[ib][jb], col-part -> comb[jb][ib].
  if (tid < 128) {
    comb_s[((size_t)ib * NB + jb) * 128 + tid] = lds_sr[tid];
    comb_t[((size_t)ib * NB + jb) * 128 + tid] = lds_tr[tid];
    if (ib != jb) {
      comb_s[((size_t)jb * NB + ib) * 128 + tid] = lds_sc[tid];
      comb_t[((size_t)jb * NB + ib) * 128 + tid] = lds_tc[tid];
    }
  }
  if (tid == 0) {
    const float w = (ib == jb) ? 1.f : 2.f;
    P_part[bid] = w * (red[0] + red[1] + red[2] + red[3] +
                       red[4] + red[5] + red[6] + red[7]);
  }
}

// 64 blocks x 512 threads: per band, fold 64 part-vectors -> band partials;
// LAST finished block does the final formula. Reset-free ticket: counter is
// never initialized; 64 consecutive atomicAdd results contain exactly one
// value with residue 63 (mod 64), deterministic per launch.
__global__ __launch_bounds__(512) void reduce_kernel(
    const float* __restrict__ comb_s, const float* __restrict__ comb_t,
    const float* __restrict__ P_part, float* __restrict__ band_acc,
    u32* __restrict__ counter, float* __restrict__ out)
{
  const int b   = blockIdx.x;
  const int tid = threadIdx.x;
  const int row = tid & 127;
  const int grp = tid >> 7;    // 0..3

  float sv = 0.f, tv = 0.f;
  for (int k = grp * 16; k < grp * 16 + 16; ++k) {
    sv += comb_s[((size_t)b * NB + k) * 128 + row];
    tv += comb_t[((size_t)b * NB + k) * 128 + row];
  }
  __shared__ float ls[4][128], lt[4][128];
  ls[grp][row] = sv;
  lt[grp][row] = tv;
  __syncthreads();

  __shared__ float r2[2][3];
  if (tid < 128) {
    float S = ls[0][row] + ls[1][row] + ls[2][row] + ls[3][row];
    float T = lt[0][row] + lt[1][row] + lt[2][row] + lt[3][row];
    float C = S * T;
    #pragma unroll
    for (int off = 1; off < 64; off <<= 1) {
      S += __shfl_xor(S, off, 64);
      T += __shfl_xor(T, off, 64);
      C += __shfl_xor(C, off, 64);
    }
    if ((tid & 63) == 0) { r2[tid >> 6][0] = S; r2[tid >> 6][1] = T; r2[tid >> 6][2] = C; }
  }
  __syncthreads();
  if (tid == 0) {
    band_acc[b * 4 + 0] = r2[0][0] + r2[1][0];
    band_acc[b * 4 + 1] = r2[0][1] + r2[1][1];
    band_acc[b * 4 + 2] = r2[0][2] + r2[1][2];
  }

  // Last-block-done final reduction (reset-free mod-64 ticket).
  __shared__ u32 ticket;
  __threadfence();
  if (tid == 0) ticket = atomicAdd(counter, 1u);
  __syncthreads();
  if ((ticket & (NB - 1)) != NB - 1) return;
  __threadfence();

  float S = 0.f, T = 0.f, C = 0.f, P = 0.f;
  if (tid < NB) {
    S = band_acc[tid * 4 + 0];
    T = band_acc[tid * 4 + 1];
    C = band_acc[tid * 4 + 2];
  }
  for (int i = tid; i < NTRI; i += 512) P += P_part[i];
  #pragma unroll
  for (int off = 1; off < 64; off <<= 1) {
    S += __shfl_xor(S, off, 64);
    T += __shfl_xor(T, off, 64);
    C += __shfl_xor(C, off, 64);
    P += __shfl_xor(P, off, 64);
  }
  __shared__ float r[8][4];
  const int w = tid >> 6;
  if ((tid & 63) == 0) { r[w][0] = S; r[w][1] = T; r[w][2] = C; r[w][3] = P; }
  __syncthreads();
  if (tid == 0) {
    double St = 0.0, Tt = 0.0, Ct = 0.0, Pt = 0.0;
    for (int i = 0; i < 8; ++i) {
      St += r[i][0]; Tt += r[i][1]; Ct += r[i][2]; Pt += r[i][3];
    }
    const double m  = (double)MM;
    const double num = Pt - (2.0 / m) * Ct + (St * Tt) / (m * m);
    out[0] = (float)(num / ((m - 1.0) * (m - 1.0)));
  }
}

extern "C" void kernel_launch(void* const* d_in, const int* in_sizes, int n_in,
                              void* d_out, int out_size, void* d_ws, size_t ws_size,
                              hipStream_t stream) {
  const float* x = (const float*)d_in[0];
  const float* y = (const float*)d_in[1];

  char* ws = (char*)d_ws;
  u16*   xb       = (u16*)ws;                                      // 2 MB
  u16*   yb       = (u16*)(ws + (size_t)2 * 1024 * 1024);          // 2 MB
  float* sqx      = (float*)(ws + (size_t)4 * 1024 * 1024);        // 32 KB
  float* sqy      = sqx + MM;                                      // 32 KB
  float* comb_s   = sqy + MM;                                      // 2 MB
  float* comb_t   = comb_s + (size_t)NB * NB * 128;                // 2 MB
  float* P_part   = comb_t + (size_t)NB * NB * 128;                // 8.3 KB
  float* band_acc = P_part + NTRI;                                 // 1 KB
  u32*   counter  = (u32*)(band_acc + NB * 4);                     // 4 B (never reset)

  convert_kernel<<<MM / 8, 256, 0, stream>>>(x, y, xb, yb, sqx, sqy);

  hsic_pair_kernel<<<NTRI, 512, 0, stream>>>(xb, yb, sqx, sqy, comb_s, comb_t, P_part);

  reduce_kernel<<<NB, 512, 0, stream>>>(comb_s, comb_t, P_part, band_acc,
                                        counter, (float*)d_out);
}

// Round 15
// 51.908 us; speedup vs baseline: 1.2747x; 1.1605x over previous
//
#include <hip/hip_runtime.h>
#include <hip/hip_bf16.h>

typedef unsigned short u16;
typedef unsigned int   u32;

#define MM 8192
#define DD 128
#define NB 64                    // 128-row bands
#define NTRI (NB * (NB + 1) / 2) // 2080 upper-triangle blocks
#define SKIP_THR -40.0f

using short8 = __attribute__((ext_vector_type(8))) short;
using f32x4  = __attribute__((ext_vector_type(4))) float;

__device__ __forceinline__ u16 f2bf(float f) {
  u32 u = __float_as_uint(f);
  u32 r = u + 0x7fffu + ((u >> 16) & 1u);   // RNE
  return (u16)(r >> 16);
}

#define GLOAD_LDS16(g, l)                                          \
  __builtin_amdgcn_global_load_lds(                                \
      (const __attribute__((address_space(1))) void*)(g),          \
      (__attribute__((address_space(3))) void*)(l), 16, 0, 0)

// One wave per 2 rows (float4 loads): bf16 conversion + squared norms.
__global__ __launch_bounds__(256) void convert_kernel(
    const float* __restrict__ x, const float* __restrict__ y,
    u16* __restrict__ xb, u16* __restrict__ yb,
    float* __restrict__ sqx, float* __restrict__ sqy)
{
  const int wid  = threadIdx.x >> 6;
  const int lane = threadIdx.x & 63;
  const int l32  = lane & 31;
  const int row  = blockIdx.x * 8 + wid * 2 + (lane >> 5);
  const float4 vx = *(const float4*)(x + (size_t)row * DD + l32 * 4);
  const float4 vy = *(const float4*)(y + (size_t)row * DD + l32 * 4);
  float sx = vx.x * vx.x + vx.y * vx.y + vx.z * vx.z + vx.w * vx.w;
  float sy = vy.x * vy.x + vy.y * vy.y + vy.z * vy.z + vy.w * vy.w;
  #pragma unroll
  for (int off = 1; off < 32; off <<= 1) {
    sx += __shfl_xor(sx, off, 64);
    sy += __shfl_xor(sy, off, 64);
  }
  uint2 px, py;
  px.x = (u32)f2bf(vx.x) | ((u32)f2bf(vx.y) << 16);
  px.y = (u32)f2bf(vx.z) | ((u32)f2bf(vx.w) << 16);
  py.x = (u32)f2bf(vy.x) | ((u32)f2bf(vy.y) << 16);
  py.y = (u32)f2bf(vy.z) | ((u32)f2bf(vy.w) << 16);
  *(uint2*)(xb + (size_t)row * DD + l32 * 4) = px;
  *(uint2*)(yb + (size_t)row * DD + l32 * 4) = py;
  if (l32 == 0) { sqx[row] = sx; sqy[row] = sy; }
}

// Upper-triangle 128x128 blocks (ib <= jb), 8 waves in 2x4, wave = 64x32.
// Best measured configuration (R12): BK=64 dbuf, 0 conflicts, 16 waves/CU,
// XCD-bijective bid swizzle, merged X-drain (4 main barriers), closed-form
// (ib,jb) map, skip-vote epilogue, band-keyed plain stores, no atomics.
__global__ __launch_bounds__(512) void hsic_pair_kernel(
    const u16* __restrict__ xb, const u16* __restrict__ yb,
    const float* __restrict__ sqx, const float* __restrict__ sqy,
    float* __restrict__ comb_s, float* __restrict__ comb_t,
    float* __restrict__ P_part)
{
  const int orig = blockIdx.x;
  const int bid  = (orig & 7) * (NTRI / 8) + (orig >> 3);   // XCD-chunked, bijective

  // bid -> (ib, jb), ib <= jb: closed form + +-1 fixup.
  int ib = (int)((2.0 * NB + 1.0 -
                  sqrt((2.0 * NB + 1.0) * (2.0 * NB + 1.0) - 8.0 * (double)bid)) * 0.5);
  if (ib > NB - 1) ib = NB - 1;
  if (ib < 0) ib = 0;
  if (ib * NB - ib * (ib - 1) / 2 > bid) --ib;
  if ((ib + 1) * NB - (ib + 1) * ib / 2 <= bid) ++ib;
  const int jb = ib + (bid - (ib * NB - ib * (ib - 1) / 2));

  const int tid  = threadIdx.x;
  const int wid  = tid >> 6;     // 0..7
  const int lane = tid & 63;
  const int wr   = wid >> 2;     // 0..1  (64-row group)
  const int wc   = wid & 3;      // 0..3  (32-col group)
  const int g    = lane >> 4;    // 0..3
  const int c    = lane & 15;    // 0..15

  const int ri = ib * 128 + wr * 64;
  const int cj = jb * 128 + wc * 32;

  __shared__ u16 lT[2][2][128 * 64];   // [buf][A/B][128 x 64] = 64 KB
  __shared__ float lds_sr[128], lds_sc[128], lds_tr[128], lds_tc[128];
  __shared__ float red[8];
  if (tid < 128) {
    lds_sr[tid] = 0.f; lds_sc[tid] = 0.f;
    lds_tr[tid] = 0.f; lds_tc[tid] = 0.f;
  }

  // Staging geometry (per 16KB sub-tile): 2 x 16B chunks per thread.
  // LDS dest linear: o = i*8192 + tid*16. Source pre-swizzled:
  //   r = o>>7, ch = (o>>4)&7, src = r*256 + (ch ^ (r&7))*16 (+kh*128).
  int so_[2];
  #pragma unroll
  for (int i = 0; i < 2; ++i) {
    const int o  = i * 8192 + tid * 16;
    const int r  = o >> 7;
    const int ch = (o >> 4) & 7;
    so_[i] = r * 256 + ((ch ^ (r & 7)) << 4);
  }

#define STAGE(BUF, GA, GB, KH) do {                                     \
    const char* gA_ = (GA) + (KH) * 128;                                \
    const char* gB_ = (GB) + (KH) * 128;                                \
    char* dA_ = (char*)&lT[BUF][0][0] + wid * 1024;                     \
    char* dB_ = (char*)&lT[BUF][1][0] + wid * 1024;                     \
    _Pragma("unroll") for (int i = 0; i < 2; ++i) {                     \
      GLOAD_LDS16(gA_ + so_[i], dA_ + i * 8192);                        \
      GLOAD_LDS16(gB_ + so_[i], dB_ + i * 8192);                        \
    }                                                                   \
  } while (0)

  // Fragment read in a 16KB sub-tile: elem = row*64 + (ch ^ (row&7))*8.
#define FRAG2(Lp, row, ch) \
  (*(const short8*)((Lp) + (((row) << 6) + (((ch) ^ ((row) & 7)) << 3))))

#define COMPUTE(ACC, BUF) do {                                          \
    _Pragma("unroll") for (int kk2 = 0; kk2 < 2; ++kk2) {               \
      short8 bfr[2], afr[4];                                            \
      _Pragma("unroll") for (int cs = 0; cs < 2; ++cs)                  \
        bfr[cs] = FRAG2(&lT[BUF][1][0], wc * 32 + cs * 16 + c, kk2 * 4 + g); \
      _Pragma("unroll") for (int rs = 0; rs < 4; ++rs)                  \
        afr[rs] = FRAG2(&lT[BUF][0][0], wr * 64 + rs * 16 + c, kk2 * 4 + g); \
      _Pragma("unroll") for (int rs = 0; rs < 4; ++rs)                  \
        _Pragma("unroll") for (int cs = 0; cs < 2; ++cs)                \
          ACC[rs][cs] = __builtin_amdgcn_mfma_f32_16x16x32_bf16(        \
              afr[rs], bfr[cs], ACC[rs][cs], 0, 0, 0);                  \
    }                                                                   \
  } while (0)

  const char* gAx = (const char*)xb + (size_t)(ib * 128) * 256;
  const char* gBx = (const char*)xb + (size_t)(jb * 128) * 256;
  const char* gAy = (const char*)yb + (size_t)(ib * 128) * 256;
  const char* gBy = (const char*)yb + (size_t)(jb * 128) * 256;

  f32x4 accX[4][2];
  f32x4 accY[4][2];
  #pragma unroll
  for (int rs = 0; rs < 4; ++rs)
    #pragma unroll
    for (int cs = 0; cs < 2; ++cs) {
      accX[rs][cs] = (f32x4){0.f, 0.f, 0.f, 0.f};
      accY[rs][cs] = (f32x4){0.f, 0.f, 0.f, 0.f};
    }

  // Pipeline (4 main barriers): both X stages drain together; Y stages
  // fly under X/Y computes.
  STAGE(0, gAx, gBx, 0);
  STAGE(1, gAx, gBx, 1);
  __syncthreads();                       // one drain for both X sub-tiles
  COMPUTE(accX, 0);
  __syncthreads();                       // all waves done reading buf0
  STAGE(0, gAy, gBy, 0);                 // Y0 flies under X1 compute
  COMPUTE(accX, 1);
  __syncthreads();                       // drains Y0; buf1 reads done
  STAGE(1, gAy, gBy, 1);                 // Y1 flies under Y0 compute
  COMPUTE(accY, 0);
  __syncthreads();                       // drains Y1
  COMPUTE(accY, 1);

  // ---- epilogue ----
  float sqxc[2], sqyc[2];
  #pragma unroll
  for (int cs = 0; cs < 2; ++cs) {
    sqxc[cs] = sqx[cj + cs * 16 + c];
    sqyc[cs] = sqy[cj + cs * 16 + c];
  }

  float p_acc = 0.f;
  float scol_acc[2] = {0.f, 0.f};
  float tcol_acc[2] = {0.f, 0.f};

  #pragma unroll
  for (int rs = 0; rs < 4; ++rs) {
    const f32x4 sxr = *(const f32x4*)(sqx + ri + rs * 16 + g * 4);
    const f32x4 syr = *(const f32x4*)(sqy + ri + rs * 16 + g * 4);

    float sr_acc[4] = {0.f, 0.f, 0.f, 0.f};
    float tr_acc[4] = {0.f, 0.f, 0.f, 0.f};
    bool rowx = false, rowy = false;

    #pragma unroll
    for (int cs = 0; cs < 2; ++cs) {
      float ex[4], ey[4];
      #pragma unroll
      for (int tt = 0; tt < 4; ++tt) {
        ex[tt] = 2.f * accX[rs][cs][tt] - sxr[tt] - sqxc[cs];
        ey[tt] = 2.f * accY[rs][cs][tt] - syr[tt] - sqyc[cs];
      }
      const float mxx = fmaxf(fmaxf(ex[0], ex[1]), fmaxf(ex[2], ex[3]));
      const float mxy = fmaxf(fmaxf(ey[0], ey[1]), fmaxf(ey[2], ey[3]));
      const bool skipx = __all(mxx < SKIP_THR);
      const bool skipy = __all(mxy < SKIP_THR);
      if (skipx && skipy) continue;   // wave-uniform

      const int gc = cj + cs * 16 + c;
      float kx[4], ly[4];
      #pragma unroll
      for (int tt = 0; tt < 4; ++tt) {
        const int gr = ri + rs * 16 + g * 4 + tt;
        kx[tt] = skipx ? 0.f : ((gr == gc) ? 1.f : __expf(ex[tt]));
        ly[tt] = skipy ? 0.f : ((gr == gc) ? 1.f : __expf(ey[tt]));
      }
      if (!skipx) {
        rowx = true;
        float sc_ = 0.f;
        #pragma unroll
        for (int tt = 0; tt < 4; ++tt) { sr_acc[tt] += kx[tt]; sc_ += kx[tt]; }
        sc_ += __shfl_xor(sc_, 16, 64);   // reduce over g-lanes
        sc_ += __shfl_xor(sc_, 32, 64);
        scol_acc[cs] += sc_;
      }
      if (!skipy) {
        rowy = true;
        float tc_ = 0.f;
        #pragma unroll
        for (int tt = 0; tt < 4; ++tt) { tr_acc[tt] += ly[tt]; tc_ += ly[tt]; }
        tc_ += __shfl_xor(tc_, 16, 64);
        tc_ += __shfl_xor(tc_, 32, 64);
        tcol_acc[cs] += tc_;
      }
      if (!skipx && !skipy) {
        #pragma unroll
        for (int tt = 0; tt < 4; ++tt) p_acc += kx[tt] * ly[tt];
      }
    }

    if (rowx) {
      #pragma unroll
      for (int tt = 0; tt < 4; ++tt) {
        float sv = sr_acc[tt];
        #pragma unroll
        for (int off = 1; off < 16; off <<= 1) sv += __shfl_xor(sv, off, 64);
        if (c == 0) atomicAdd(&lds_sr[wr * 64 + rs * 16 + g * 4 + tt], sv);
      }
    }
    if (rowy) {
      #pragma unroll
      for (int tt = 0; tt < 4; ++tt) {
        float tv = tr_acc[tt];
        #pragma unroll
        for (int off = 1; off < 16; off <<= 1) tv += __shfl_xor(tv, off, 64);
        if (c == 0) atomicAdd(&lds_tr[wr * 64 + rs * 16 + g * 4 + tt], tv);
      }
    }
  }

  // Column sums (band jb rows via symmetry).
  if (g == 0) {
    #pragma unroll
    for (int cs = 0; cs < 2; ++cs) {
      atomicAdd(&lds_sc[wc * 32 + cs * 16 + c], scol_acc[cs]);
      atomicAdd(&lds_tc[wc * 32 + cs * 16 + c], tcol_acc[cs]);
    }
  }

  // Block-reduce P.
  #pragma unroll
  for (int off = 1; off < 64; off <<= 1) p_acc += __shfl_xor(p_acc, off, 64);
  if (lane == 0) red[wid] = p_acc;
  __syncthreads();

  // Band-keyed plain stores: row-part -> comb[ib][jb], col-part -> comb[jb][ib].
  if (tid < 128) {
    comb_s[((size_t)ib * NB + jb) * 128 + tid] = lds_sr[tid];
    comb_t[((size_t)ib * NB + jb) * 128 + tid] = lds_tr[tid];
    if (ib != jb) {
      comb_s[((size_t)jb * NB + ib) * 128 + tid] = lds_sc[tid];
      comb_t[((size_t)jb * NB + ib) * 128 + tid] = lds_tc[tid];
    }
  }
  if (tid == 0) {
    const float w = (ib == jb) ? 1.f : 2.f;
    P_part[bid] = w * (red[0] + red[1] + red[2] + red[3] +
                       red[4] + red[5] + red[6] + red[7]);
  }
}

// 64 blocks x 512 threads: per band, fold 64 part-vectors -> row sums ->
// band partials (S, T, sum(s*t)). Fully coalesced, no atomics.
__global__ __launch_bounds__(512) void reduce1_kernel(
    const float* __restrict__ comb_s, const float* __restrict__ comb_t,
    float* __restrict__ band_acc)
{
  const int b   = blockIdx.x;
  const int tid = threadIdx.x;
  const int row = tid & 127;
  const int grp = tid >> 7;    // 0..3

  float sv = 0.f, tv = 0.f;
  for (int k = grp * 16; k < grp * 16 + 16; ++k) {
    sv += comb_s[((size_t)b * NB + k) * 128 + row];
    tv += comb_t[((size_t)b * NB + k) * 128 + row];
  }
  __shared__ float ls[4][128], lt[4][128];
  ls[grp][row] = sv;
  lt[grp][row] = tv;
  __syncthreads();

  __shared__ float r2[2][3];
  if (tid < 128) {
    float S = ls[0][row] + ls[1][row] + ls[2][row] + ls[3][row];
    float T = lt[0][row] + lt[1][row] + lt[2][row] + lt[3][row];
    float C = S * T;
    #pragma unroll
    for (int off = 1; off < 64; off <<= 1) {
      S += __shfl_xor(S, off, 64);
      T += __shfl_xor(T, off, 64);
      C += __shfl_xor(C, off, 64);
    }
    if ((tid & 63) == 0) { r2[tid >> 6][0] = S; r2[tid >> 6][1] = T; r2[tid >> 6][2] = C; }
  }
  __syncthreads();
  if (tid == 0) {
    band_acc[b * 4 + 0] = r2[0][0] + r2[1][0];
    band_acc[b * 4 + 1] = r2[0][1] + r2[1][1];
    band_acc[b * 4 + 2] = r2[0][2] + r2[1][2];
  }
}

// One block: sum band partials + P parts, final formula in double.
__global__ __launch_bounds__(256) void reduce2_kernel(
    const float* __restrict__ band_acc, const float* __restrict__ P_part,
    float* __restrict__ out)
{
  const int tid = threadIdx.x;
  float S = 0.f, T = 0.f, C = 0.f, P = 0.f;
  if (tid < NB) {
    S = band_acc[tid * 4 + 0];
    T = band_acc[tid * 4 + 1];
    C = band_acc[tid * 4 + 2];
  }
  for (int i = tid; i < NTRI; i += 256) P += P_part[i];
  #pragma unroll
  for (int off = 1; off < 64; off <<= 1) {
    S += __shfl_xor(S, off, 64);
    T += __shfl_xor(T, off, 64);
    C += __shfl_xor(C, off, 64);
    P += __shfl_xor(P, off, 64);
  }
  __shared__ float r[4][4];
  const int w = tid >> 6;
  if ((tid & 63) == 0) { r[w][0] = S; r[w][1] = T; r[w][2] = C; r[w][3] = P; }
  __syncthreads();
  if (tid == 0) {
    const double St = (double)r[0][0] + r[1][0] + r[2][0] + r[3][0];
    const double Tt = (double)r[0][1] + r[1][1] + r[2][1] + r[3][1];
    const double Ct = (double)r[0][2] + r[1][2] + r[2][2] + r[3][2];
    const double Pt = (double)r[0][3] + r[1][3] + r[2][3] + r[3][3];
    const double m  = (double)MM;
    const double num = Pt - (2.0 / m) * Ct + (St * Tt) / (m * m);
    out[0] = (float)(num / ((m - 1.0) * (m - 1.0)));
  }
}

extern "C" void kernel_launch(void* const* d_in, const int* in_sizes, int n_in,
                              void* d_out, int out_size, void* d_ws, size_t ws_size,
                              hipStream_t stream) {
  const float* x = (const float*)d_in[0];
  const float* y = (const float*)d_in[1];

  char* ws = (char*)d_ws;
  u16*   xb       = (u16*)ws;                                      // 2 MB
  u16*   yb       = (u16*)(ws + (size_t)2 * 1024 * 1024);          // 2 MB
  float* sqx      = (float*)(ws + (size_t)4 * 1024 * 1024);        // 32 KB
  float* sqy      = sqx + MM;                                      // 32 KB
  float* comb_s   = sqy + MM;                                      // 2 MB
  float* comb_t   = comb_s + (size_t)NB * NB * 128;                // 2 MB
  float* P_part   = comb_t + (size_t)NB * NB * 128;                // 8.3 KB
  float* band_acc = P_part + NTRI;                                 // 1 KB

  convert_kernel<<<MM / 8, 256, 0, stream>>>(x, y, xb, yb, sqx, sqy);

  hsic_pair_kernel<<<NTRI, 512, 0, stream>>>(xb, yb, sqx, sqy, comb_s, comb_t, P_part);

  reduce1_kernel<<<NB, 512, 0, stream>>>(comb_s, comb_t, band_acc);
  reduce2_kernel<<<1, 256, 0, stream>>>(band_acc, P_part, (float*)d_out);
}